// Round 9
// baseline (115.513 us; speedup 1.0000x reference)
//
#include <hip/hip_runtime.h>
#include <hip/hip_bf16.h>
#include <math.h>

#define C_DIM 1024
#define CR    256
#define A_N   10
#define NANCH 3
#define B_N   2
#define HW_N  4096
#define NTOK  (B_N*HW_N)   // 8192
#define KG2   (A_N*CR)     // 2560

typedef unsigned short ushort_t;
typedef __attribute__((ext_vector_type(4))) float f32x4;
typedef __attribute__((ext_vector_type(8))) short bf16x8;

__device__ __forceinline__ ushort_t f2bf(float x) {
    __hip_bfloat16 h = __float2bfloat16(x);
    return *reinterpret_cast<ushort_t*>(&h);
}
__device__ __forceinline__ float bf2f(ushort_t u) {
    return __uint_as_float(((unsigned)u) << 16);
}

// tanh-form GELU via sigmoid identity; |err| < ~1e-3 (below bf16 rounding)
__device__ __forceinline__ float fast_gelu(float x) {
    float t = x * x;
    float u = x * (-1.5957691216f - 0.0713548163f * t);
    float e = __expf(u);
    return x * __frcp_rn(1.0f + e);
}

// ================= consolidated prep kernel (ATOMIC-FREE, no zero-init) =======
// block 0          : wsel compaction + tokmap + cnt (single block, LDS counters)
// blocks [1,641)   : w1t transpose + bias1P/cs1P PARTIALS (one slot per c-block)
// blocks [641,1281): w2t transpose
// blocks [1281,3329): LN partial sums -> sums[t][32] slots + featT transpose
__global__ __launch_bounds__(256) void prep_all(
    const float* __restrict__ w1, const float* __restrict__ w2,
    const float* __restrict__ ln_s, const float* __restrict__ ln_b,
    const float* __restrict__ feat, const float* __restrict__ ar,
    ushort_t* __restrict__ w1t, ushort_t* __restrict__ w2t,
    float* __restrict__ bias1P, float* __restrict__ cs1P,
    float* __restrict__ sums,
    int* __restrict__ cnt, int* __restrict__ tokw, int* __restrict__ tokmap,
    ushort_t* __restrict__ featT) {
    __shared__ float lds[64][65];
    __shared__ float bb[8][64];
    __shared__ int lpos[A_N];
    int id = blockIdx.x, tid = threadIdx.x;
    int lo = tid & 63, hi = tid >> 6;

    if (id == 0) {                        // ---- wsel: single block, no global atomics ----
        if (tid < A_N) lpos[tid] = 0;
        __syncthreads();
        const float THR[9] = {1.0f/9.0f, 1.0f/7.0f, 0.2f, 1.0f/3.0f, 1.0f, 3.0f, 5.0f, 7.0f, 9.0f};
        for (int it = 0; it < NTOK / 256; ++it) {
            int t = it * 256 + tid;
            int b = t >> 12, p = t & (HW_N - 1);
            int idxs[NANCH];
            #pragma unroll
            for (int na = 0; na < NANCH; na++) {
                float v = ar[(size_t)b * NANCH * HW_N + na * HW_N + p];
                int idx = 0;
                #pragma unroll
                for (int i = 0; i < 9; i++) idx += (v > THR[i]) ? 1 : 0;
                idxs[na] = idx;
            }
            #pragma unroll
            for (int j = 0; j < NANCH; j++) {
                bool first = true; int c3 = 0;
                #pragma unroll
                for (int k = 0; k < NANCH; k++) {
                    if (idxs[k] == idxs[j]) { c3++; if (k < j) first = false; }
                }
                int e = 0;
                if (first) {
                    int a2 = idxs[j];
                    int pos = atomicAdd(&lpos[a2], 1);      // LDS atomic
                    tokw[a2 * NTOK + pos] = t;
                    e = pos | (a2 << 13) | (c3 << 17);
                }
                tokmap[t * 3 + j] = e;                      // e=0 -> weight 0, ignored
            }
        }
        __syncthreads();
        if (tid < A_N) cnt[tid] = lpos[tid];
    } else if (id < 641) {                // ---- prep_w1t + bias1P/cs1P partials ----
        int id2 = id - 1;
        int d0 = (id2 & 3) * 64, c0idx = (id2 >> 2) & 15, a = id2 >> 6;
        int c0 = c0idx * 64;
        #pragma unroll
        for (int i = 0; i < 16; i++) {
            int c_l = i * 4 + hi;
            lds[c_l][lo] = w1[((size_t)a * C_DIM + c0 + c_l) * CR + d0 + lo];  // raw
        }
        __syncthreads();
        {
            float s = 0.f, s2 = 0.f;
            #pragma unroll
            for (int cc = 0; cc < 16; cc++) {
                int c = hi * 16 + cc;
                float v = lds[c][lo];
                s  += v * ln_b[a * C_DIM + c0 + c];
                s2 += v * ln_s[a * C_DIM + c0 + c];
            }
            bb[hi][lo] = s;
            bb[hi + 4][lo] = s2;
        }
        float sc = ln_s[a * C_DIM + c0 + lo];
        #pragma unroll
        for (int i = 0; i < 16; i++) {
            int d_l = i * 4 + hi;
            w1t[((size_t)a * CR + d0 + d_l) * C_DIM + c0 + lo] = f2bf(lds[lo][d_l] * sc);
        }
        __syncthreads();
        // one partial slot per (col, c-block): written exactly once, no atomic, no zero
        if (hi == 0)
            bias1P[(size_t)(a * CR + d0 + lo) * 16 + c0idx] =
                bb[0][lo] + bb[1][lo] + bb[2][lo] + bb[3][lo];
        else if (hi == 1)
            cs1P[(size_t)(a * CR + d0 + lo) * 16 + c0idx] =
                bb[4][lo] + bb[5][lo] + bb[6][lo] + bb[7][lo];
    } else if (id < 1281) {               // ---- prep_w2t ----
        int id2 = id - 641;
        int k0 = (id2 % 40) * 64, c0 = (id2 / 40) * 64;
        #pragma unroll
        for (int i = 0; i < 16; i++) {
            int k_l = i * 4 + hi;
            lds[k_l][lo] = w2[((size_t)k0 + k_l) * C_DIM + c0 + lo];
        }
        __syncthreads();
        #pragma unroll
        for (int i = 0; i < 16; i++) {
            int c_l = i * 4 + hi;
            w2t[((size_t)c0 + c_l) * KG2 + k0 + lo] = f2bf(lds[lo][c_l]);
        }
    } else {                              // ---- LN partial sums + featT transpose ----
        int id2 = id - 1281;
        int p0 = (id2 & 63) * 64, c0idx = (id2 >> 6) & 15, b = id2 >> 10;
        int c0 = c0idx * 64;
        #pragma unroll
        for (int i = 0; i < 16; i++) {
            int c_l = i * 4 + hi;
            lds[c_l][lo] = feat[((size_t)b * C_DIM + c0 + c_l) * HW_N + p0 + lo];
        }
        __syncthreads();
        {
            float s = 0.f, s2 = 0.f;
            #pragma unroll
            for (int c = hi; c < 64; c += 4) {
                float v = lds[c][lo];
                s += v; s2 += v * v;
            }
            bb[hi][lo] = s; bb[hi + 4][lo] = s2;
        }
        __syncthreads();
        if (tid < 64) {
            float ss = bb[0][tid] + bb[1][tid] + bb[2][tid] + bb[3][tid];
            float qq = bb[4][tid] + bb[5][tid] + bb[6][tid] + bb[7][tid];
            int t = b * HW_N + p0 + tid;
            sums[(size_t)t * 32 + c0idx] = ss;        // slot write, no atomic
            sums[(size_t)t * 32 + 16 + c0idx] = qq;
        }
        // transpose-write raw bf16 featT (token-major), vectorized 16B stores
        int t_l = tid >> 3, cg = tid & 7;
        #pragma unroll
        for (int ii = 0; ii < 2; ii++) {
            int tl = ii * 32 + t_l;
            bf16x8 v;
            #pragma unroll
            for (int k = 0; k < 8; k++)
                v[k] = (short)f2bf(lds[cg * 8 + k][tl]);
            *(bf16x8*)(featT + (size_t)(b * HW_N + p0 + tl) * C_DIM + c0 + cg * 8) = v;
        }
    }
}

// ======== 128x128 bf16 MFMA core, BK=64 (m97 single-buffer structure) ========
__device__ __forceinline__ void gemm_core_ptrs(
    const ushort_t* const ap[4], const ushort_t* const bp[4],
    int K, ushort_t* As, ushort_t* Bs, f32x4 acc[4][4]) {
    const int tid = threadIdx.x;
    const int lane = tid & 63;
    const int w = tid >> 6;
    const int wr = w >> 1, wc = w & 1;
    const int lrow = lane & 15;
    const int quad = lane >> 4;
    const int swzr = lrow & 7;

    #pragma unroll
    for (int i = 0; i < 4; i++)
        #pragma unroll
        for (int j = 0; j < 4; j++)
            #pragma unroll
            for (int e = 0; e < 4; e++) acc[i][j][e] = 0.f;

    for (int k0 = 0; k0 < K; k0 += 64) {
        __syncthreads();
        #pragma unroll
        for (int i = 0; i < 4; i++) {
            __builtin_amdgcn_global_load_lds(
                (__attribute__((address_space(1))) void*)(ap[i] + k0),
                (__attribute__((address_space(3))) void*)(As + (w * 32 + i * 8) * 64),
                16, 0, 0);
            __builtin_amdgcn_global_load_lds(
                (__attribute__((address_space(1))) void*)(bp[i] + k0),
                (__attribute__((address_space(3))) void*)(Bs + (w * 32 + i * 8) * 64),
                16, 0, 0);
        }
        __syncthreads();
        #pragma unroll
        for (int ks = 0; ks < 2; ks++) {
            const int cidx = ((ks * 4 + quad) ^ swzr) * 8;
            bf16x8 af[4], bfr[4];
            #pragma unroll
            for (int mt = 0; mt < 4; mt++)
                af[mt] = *(const bf16x8*)(As + (wr * 64 + mt * 16 + lrow) * 64 + cidx);
            #pragma unroll
            for (int nt = 0; nt < 4; nt++)
                bfr[nt] = *(const bf16x8*)(Bs + (wc * 64 + nt * 16 + lrow) * 64 + cidx);
            #pragma unroll
            for (int mt = 0; mt < 4; mt++)
                #pragma unroll
                for (int nt = 0; nt < 4; nt++)
                    acc[mt][nt] = __builtin_amdgcn_mfma_f32_16x16x32_bf16(af[mt], bfr[nt], acc[mt][nt], 0, 0, 0);
        }
    }
}

// ======== 128x128 core, BK=128 as two 64-wide panels per barrier pair ========
__device__ __forceinline__ void gemm_core_bk128(
    const ushort_t* const ap[4], const ushort_t* const bp[4],
    int K, ushort_t* As, ushort_t* Bs, f32x4 acc[4][4]) {
    const int tid = threadIdx.x;
    const int lane = tid & 63;
    const int w = tid >> 6;
    const int wr = w >> 1, wc = w & 1;
    const int lrow = lane & 15;
    const int quad = lane >> 4;
    const int swzr = lrow & 7;

    #pragma unroll
    for (int i = 0; i < 4; i++)
        #pragma unroll
        for (int j = 0; j < 4; j++)
            #pragma unroll
            for (int e = 0; e < 4; e++) acc[i][j][e] = 0.f;

    for (int k0 = 0; k0 < K; k0 += 128) {
        __syncthreads();
        #pragma unroll
        for (int p = 0; p < 2; p++) {
            #pragma unroll
            for (int i = 0; i < 4; i++) {
                __builtin_amdgcn_global_load_lds(
                    (__attribute__((address_space(1))) void*)(ap[i] + k0 + p * 64),
                    (__attribute__((address_space(3))) void*)(As + p * 8192 + (w * 32 + i * 8) * 64),
                    16, 0, 0);
                __builtin_amdgcn_global_load_lds(
                    (__attribute__((address_space(1))) void*)(bp[i] + k0 + p * 64),
                    (__attribute__((address_space(3))) void*)(Bs + p * 8192 + (w * 32 + i * 8) * 64),
                    16, 0, 0);
            }
        }
        __syncthreads();
        #pragma unroll
        for (int ks = 0; ks < 4; ks++) {
            const ushort_t* Ab = As + (ks >> 1) * 8192;
            const ushort_t* Bb = Bs + (ks >> 1) * 8192;
            const int cidx = (((ks & 1) * 4 + quad) ^ swzr) * 8;
            bf16x8 af[4], bfr[4];
            #pragma unroll
            for (int mt = 0; mt < 4; mt++)
                af[mt] = *(const bf16x8*)(Ab + (wr * 64 + mt * 16 + lrow) * 64 + cidx);
            #pragma unroll
            for (int nt = 0; nt < 4; nt++)
                bfr[nt] = *(const bf16x8*)(Bb + (wc * 64 + nt * 16 + lrow) * 64 + cidx);
            #pragma unroll
            for (int mt = 0; mt < 4; mt++)
                #pragma unroll
                for (int nt = 0; nt < 4; nt++)
                    acc[mt][nt] = __builtin_amdgcn_mfma_f32_16x16x32_bf16(af[mt], bfr[nt], acc[mt][nt], 0, 0, 0);
        }
    }
}

// GEMM1 (compacted M, raw-feat input, LN fused; partial-slot reduction in LDS):
// Hc[base_a + i][d] = gelu( r_t*(featT[tok_i] @ w1s[a] - m_t*cs1[a]) + bias1[a] )
__global__ __launch_bounds__(256) void gemm1c(const ushort_t* __restrict__ featT,
                                              const ushort_t* __restrict__ w1t,
                                              const float* __restrict__ bias1P,
                                              const float* __restrict__ cs1P,
                                              const float* __restrict__ sums,
                                              const int* __restrict__ tokw,
                                              const int* __restrict__ cnt,
                                              ushort_t* __restrict__ Hc) {
    int a = blockIdx.z;
    int mcount = cnt[a];
    int m0 = blockIdx.y * 128;
    if (m0 >= mcount) return;
    int n0 = blockIdx.x * 128;
    int base = 0;
    for (int a2 = 0; a2 < a; a2++) base += cnt[a2];

    __shared__ __align__(16) ushort_t As[2 * 128 * 64];
    __shared__ __align__(16) ushort_t Bs[2 * 128 * 64];
    __shared__ float rowM[128], rowR[128], colB[128], colC[128];

    int tid = threadIdx.x, lane = tid & 63, w = tid >> 6;
    int lrow8 = lane >> 3;
    int scol = ((lane & 7) ^ lrow8) * 8;
    int srowl = w * 32 + lrow8;

    const ushort_t* ap[4];
    const ushort_t* bp[4];
    #pragma unroll
    for (int i = 0; i < 4; i++) {
        int rt = tokw[a * NTOK + m0 + srowl + i * 8] & (NTOK - 1);
        ap[i] = featT + (size_t)rt * C_DIM + scol;
        bp[i] = w1t + ((size_t)a * CR + n0 + srowl + i * 8) * C_DIM + scol;
    }

    f32x4 acc[4][4];
    gemm_core_bk128(ap, bp, C_DIM, As, Bs, acc);

    // reduce the 16 partial slots per row (LN stats) and per col (bias/colsum)
    if (tid < 128) {
        int t = tokw[a * NTOK + m0 + tid] & (NTOK - 1);
        const f32x4* sp = (const f32x4*)(sums + (size_t)t * 32);
        f32x4 sv = sp[0] + sp[1] + sp[2] + sp[3];
        f32x4 sq = sp[4] + sp[5] + sp[6] + sp[7];
        float m = (sv[0] + sv[1] + sv[2] + sv[3]) * (1.f / C_DIM);
        float q = (sq[0] + sq[1] + sq[2] + sq[3]) * (1.f / C_DIM);
        rowM[tid] = m;
        rowR[tid] = rsqrtf(q - m * m + 1e-5f);
    } else {
        int j = tid - 128;
        size_t col = (size_t)(a * CR + n0 + j);
        const f32x4* bp4 = (const f32x4*)(bias1P + col * 16);
        const f32x4* cp4 = (const f32x4*)(cs1P + col * 16);
        f32x4 b4 = bp4[0] + bp4[1] + bp4[2] + bp4[3];
        f32x4 c4 = cp4[0] + cp4[1] + cp4[2] + cp4[3];
        colB[j] = b4[0] + b4[1] + b4[2] + b4[3];
        colC[j] = c4[0] + c4[1] + c4[2] + c4[3];
    }
    __syncthreads();

    int wr = w >> 1, wc = w & 1, lrow = lane & 15, quad = lane >> 4;
    float bi[4], cs[4];
    #pragma unroll
    for (int nt = 0; nt < 4; nt++) {
        int cl = wc * 64 + nt * 16 + lrow;
        bi[nt] = colB[cl];
        cs[nt] = colC[cl];
    }
    #pragma unroll
    for (int mt = 0; mt < 4; mt++)
        #pragma unroll
        for (int r = 0; r < 4; r++) {
            int rl = wr * 64 + mt * 16 + quad * 4 + r;
            int i_row = m0 + rl;
            bool live = i_row < mcount;
            float m = rowM[rl];
            float rn = rowR[rl];
            #pragma unroll
            for (int nt = 0; nt < 4; nt++) {
                int col = n0 + wc * 64 + nt * 16 + lrow;
                float v = rn * (acc[mt][nt][r] - m * cs[nt]) + bi[nt];
                if (live)
                    Hc[(size_t)(base + i_row) * CR + col] = f2bf(fast_gelu(v));
            }
        }
}

// GEMM2 (compacted, per-adapter K=256, BK=64): O[base_a + i][c] = Hc_a[i] @ w2[a]
__global__ __launch_bounds__(256) void gemm2c(const ushort_t* __restrict__ Hc,
                                              const ushort_t* __restrict__ w2t,
                                              const int* __restrict__ cnt,
                                              ushort_t* __restrict__ O) {
    int a = blockIdx.z;
    int mcount = cnt[a];
    int m0 = blockIdx.y * 128;
    if (m0 >= mcount) return;
    int n0 = blockIdx.x * 128;
    int base = 0;
    for (int a2 = 0; a2 < a; a2++) base += cnt[a2];

    __shared__ __align__(16) ushort_t As[128 * 64];
    __shared__ __align__(16) ushort_t Bs[128 * 64];

    int tid = threadIdx.x, lane = tid & 63, w = tid >> 6;
    int lrow8 = lane >> 3;
    int scol = ((lane & 7) ^ lrow8) * 8;
    int srowl = w * 32 + lrow8;

    const ushort_t* ap[4];
    const ushort_t* bp[4];
    #pragma unroll
    for (int i = 0; i < 4; i++) {
        ap[i] = Hc + (size_t)(base + m0 + srowl + i * 8) * CR + scol;
        bp[i] = w2t + (size_t)(n0 + srowl + i * 8) * KG2 + a * CR + scol;
    }

    f32x4 acc[4][4];
    gemm_core_ptrs(ap, bp, CR, As, Bs, acc);

    int wr = w >> 1, wc = w & 1, lrow = lane & 15, quad = lane >> 4;
    #pragma unroll
    for (int mt = 0; mt < 4; mt++)
        #pragma unroll
        for (int r = 0; r < 4; r++) {
            int i_row = m0 + wr * 64 + mt * 16 + quad * 4 + r;
            bool live = i_row < mcount;
            #pragma unroll
            for (int nt = 0; nt < 4; nt++) {
                int col = n0 + wc * 64 + nt * 16 + lrow;
                if (live)
                    O[(size_t)(base + i_row) * C_DIM + col] = f2bf(acc[mt][nt][r]);
            }
        }
}

// final gather: out[b][c][p] = feat + sum_j w_j * O[gpos_j(t)][c]
__global__ __launch_bounds__(256) void finalk2(const ushort_t* __restrict__ O,
                                               const int* __restrict__ tokmap,
                                               const int* __restrict__ cnt,
                                               const float* __restrict__ feat,
                                               float* __restrict__ out) {
    int p0 = blockIdx.x * 64, c0 = blockIdx.y * 64, b = blockIdx.z;
    __shared__ float lds[64][65];
    __shared__ int pbase[A_N];
    int tid = threadIdx.x, lo = tid & 63, hi = tid >> 6;
    if (tid < A_N) {
        int s = 0;
        for (int k = 0; k < tid; k++) s += cnt[k];
        pbase[tid] = s;
    }
    __syncthreads();
    int t_l = tid >> 3, cg = tid & 7;
    #pragma unroll
    for (int ii = 0; ii < 2; ii++) {
        int tl = ii * 32 + t_l;
        int t = b * HW_N + p0 + tl;
        float val8[8];
        #pragma unroll
        for (int k = 0; k < 8; k++) val8[k] = 0.f;
        #pragma unroll
        for (int j = 0; j < 3; j++) {
            int e = tokmap[t * 3 + j];
            float wv = (float)(e >> 17) * (1.0f / 3.0f);
            int a2 = (e >> 13) & 15;
            int row = pbase[a2] + (e & 8191);
            bf16x8 v = *(const bf16x8*)(O + (size_t)row * C_DIM + c0 + cg * 8);
            #pragma unroll
            for (int k = 0; k < 8; k++)
                val8[k] += wv * bf2f((ushort_t)v[k]);
        }
        #pragma unroll
        for (int k = 0; k < 8; k++)
            lds[tl][cg * 8 + k] = val8[k];      // 2-way bank alias max (free, m136)
    }
    __syncthreads();
    #pragma unroll
    for (int i = 0; i < 16; i++) {
        int c_l = i * 4 + hi;
        size_t o = ((size_t)b * C_DIM + c0 + c_l) * HW_N + p0 + lo;
        out[o] = lds[lo][c_l] + feat[o];
    }
}

// ---------------- launch ----------------
extern "C" void kernel_launch(void* const* d_in, const int* in_sizes, int n_in,
                              void* d_out, int out_size, void* d_ws, size_t ws_size,
                              hipStream_t stream) {
    (void)in_sizes; (void)n_in; (void)out_size; (void)ws_size;
    const float* feat = (const float*)d_in[0];
    const float* ar   = (const float*)d_in[1];
    const float* ln_s = (const float*)d_in[2];
    const float* ln_b = (const float*)d_in[3];
    const float* w1   = (const float*)d_in[4];
    const float* w2   = (const float*)d_in[5];
    float* out = (float*)d_out;
    char* ws = (char*)d_ws;

    // ---- all buffers uninitialized (every slot written each run; no memset) ----
    int*      cnt    = (int*)(ws + 0);            // 64 B (padded)
    int*      tokmap = (int*)(ws + 64);           // 98,304   -> 98,368
    int*      tokw   = (int*)(ws + 98368);        // 327,680  -> 426,048
    ushort_t* w1t    = (ushort_t*)(ws + 426048);  // 5,242,880 -> 5,668,928
    ushort_t* w2t    = (ushort_t*)(ws + 5668928); // 5,242,880 -> 10,911,808
    ushort_t* featT  = (ushort_t*)(ws + 10911808);// 16,777,216 -> 27,689,024
    ushort_t* Hc     = (ushort_t*)(ws + 27689024);// 12,648,448 -> 40,337,472
    ushort_t* O      = (ushort_t*)(ws + 40337472);// 50,331,648 -> 90,669,120
    // partials live INSIDE O's region: written by prep, read by gemm1c, and O is
    // only written by gemm2c afterwards (disjoint lifetimes, stream-ordered).
    float*    sums   = (float*)O;                      // 8192*32*4 = 1,048,576
    float*    bias1P = (float*)((char*)O + 1048576);   // 2560*16*4 = 163,840
    float*    cs1P   = (float*)((char*)O + 1212416);   // 163,840 (ends 1,376,256)

    dim3 blk(256);
    prep_all<<<dim3(3329), blk, 0, stream>>>(w1, w2, ln_s, ln_b, feat, ar,
                                             w1t, w2t, bias1P, cs1P, sums,
                                             cnt, tokw, tokmap, featT);
    gemm1c<<<dim3(2, 64, A_N), blk, 0, stream>>>(featT, w1t, bias1P, cs1P, sums,
                                                 tokw, cnt, Hc);
    gemm2c<<<dim3(8, 64, A_N), blk, 0, stream>>>(Hc, w2t, cnt, O);
    finalk2<<<dim3(64, 16, B_N), blk, 0, stream>>>(O, tokmap, cnt, feat, out);
}

// Round 10
// 105.413 us; speedup vs baseline: 1.0958x; 1.0958x over previous
//
#include <hip/hip_runtime.h>
#include <hip/hip_bf16.h>
#include <math.h>

#define C_DIM 1024
#define CR    256
#define A_N   10
#define NANCH 3
#define B_N   2
#define HW_N  4096
#define NTOK  (B_N*HW_N)   // 8192
#define KG2   (A_N*CR)     // 2560

typedef unsigned short ushort_t;
typedef __attribute__((ext_vector_type(4))) float f32x4;
typedef __attribute__((ext_vector_type(8))) short bf16x8;

__device__ __forceinline__ ushort_t f2bf(float x) {
    __hip_bfloat16 h = __float2bfloat16(x);
    return *reinterpret_cast<ushort_t*>(&h);
}
__device__ __forceinline__ float bf2f(ushort_t u) {
    return __uint_as_float(((unsigned)u) << 16);
}

// tanh-form GELU via sigmoid identity; |err| < ~1e-3 (below bf16 rounding)
__device__ __forceinline__ float fast_gelu(float x) {
    float t = x * x;
    float u = x * (-1.5957691216f - 0.0713548163f * t);
    float e = __expf(u);
    return x * __frcp_rn(1.0f + e);
}

// zero cnt only (40 B): the sole remaining atomic target needing init
__global__ __launch_bounds__(64) void zerok(int* __restrict__ cnt) {
    if (threadIdx.x < A_N) cnt[threadIdx.x] = 0;
}

// ================= consolidated prep kernel =================
// blocks [0,640)   : w1t transpose + bias1P/cs1P PARTIAL slots (no atomics)
// blocks [640,1280): w2t transpose
// blocks [1280,3328): LN partial sums -> sums[t][32] slots (no atomics) + featT
// blocks [3328,3360): wsel compaction (32 blocks, global cnt atomics) + tokmap
__global__ __launch_bounds__(256) void prep_all(
    const float* __restrict__ w1, const float* __restrict__ w2,
    const float* __restrict__ ln_s, const float* __restrict__ ln_b,
    const float* __restrict__ feat, const float* __restrict__ ar,
    ushort_t* __restrict__ w1t, ushort_t* __restrict__ w2t,
    float* __restrict__ bias1P, float* __restrict__ cs1P,
    float* __restrict__ sums,
    int* __restrict__ cnt, int* __restrict__ tokw, int* __restrict__ tokmap,
    ushort_t* __restrict__ featT) {
    __shared__ float lds[64][65];
    __shared__ float bb[8][64];
    __shared__ int lcnt[A_N], lpos[A_N], gbase[A_N];
    int id = blockIdx.x, tid = threadIdx.x;
    int lo = tid & 63, hi = tid >> 6;

    if (id < 640) {                       // ---- prep_w1t + bias1P/cs1P partials ----
        int d0 = (id & 3) * 64, c0idx = (id >> 2) & 15, a = id >> 6;
        int c0 = c0idx * 64;
        #pragma unroll
        for (int i = 0; i < 16; i++) {
            int c_l = i * 4 + hi;
            lds[c_l][lo] = w1[((size_t)a * C_DIM + c0 + c_l) * CR + d0 + lo];  // raw
        }
        __syncthreads();
        {
            float s = 0.f, s2 = 0.f;
            #pragma unroll
            for (int cc = 0; cc < 16; cc++) {
                int c = hi * 16 + cc;
                float v = lds[c][lo];
                s  += v * ln_b[a * C_DIM + c0 + c];
                s2 += v * ln_s[a * C_DIM + c0 + c];
            }
            bb[hi][lo] = s;
            bb[hi + 4][lo] = s2;
        }
        float sc = ln_s[a * C_DIM + c0 + lo];
        #pragma unroll
        for (int i = 0; i < 16; i++) {
            int d_l = i * 4 + hi;
            w1t[((size_t)a * CR + d0 + d_l) * C_DIM + c0 + lo] = f2bf(lds[lo][d_l] * sc);
        }
        __syncthreads();
        // one partial slot per (col, c-block): written exactly once, no atomic, no zero
        if (hi == 0)
            bias1P[(size_t)(a * CR + d0 + lo) * 16 + c0idx] =
                bb[0][lo] + bb[1][lo] + bb[2][lo] + bb[3][lo];
        else if (hi == 1)
            cs1P[(size_t)(a * CR + d0 + lo) * 16 + c0idx] =
                bb[4][lo] + bb[5][lo] + bb[6][lo] + bb[7][lo];
    } else if (id < 1280) {               // ---- prep_w2t ----
        int id2 = id - 640;
        int k0 = (id2 % 40) * 64, c0 = (id2 / 40) * 64;
        #pragma unroll
        for (int i = 0; i < 16; i++) {
            int k_l = i * 4 + hi;
            lds[k_l][lo] = w2[((size_t)k0 + k_l) * C_DIM + c0 + lo];
        }
        __syncthreads();
        #pragma unroll
        for (int i = 0; i < 16; i++) {
            int c_l = i * 4 + hi;
            w2t[((size_t)c0 + c_l) * KG2 + k0 + lo] = f2bf(lds[lo][c_l]);
        }
    } else if (id < 3328) {               // ---- LN partial sums + featT transpose ----
        int id2 = id - 1280;
        int p0 = (id2 & 63) * 64, c0idx = (id2 >> 6) & 15, b = id2 >> 10;
        int c0 = c0idx * 64;
        #pragma unroll
        for (int i = 0; i < 16; i++) {
            int c_l = i * 4 + hi;
            lds[c_l][lo] = feat[((size_t)b * C_DIM + c0 + c_l) * HW_N + p0 + lo];
        }
        __syncthreads();
        {
            float s = 0.f, s2 = 0.f;
            #pragma unroll
            for (int c = hi; c < 64; c += 4) {
                float v = lds[c][lo];
                s += v; s2 += v * v;
            }
            bb[hi][lo] = s; bb[hi + 4][lo] = s2;
        }
        __syncthreads();
        if (tid < 64) {
            float ss = bb[0][tid] + bb[1][tid] + bb[2][tid] + bb[3][tid];
            float qq = bb[4][tid] + bb[5][tid] + bb[6][tid] + bb[7][tid];
            int t = b * HW_N + p0 + tid;
            sums[(size_t)t * 32 + c0idx] = ss;        // slot write, no atomic
            sums[(size_t)t * 32 + 16 + c0idx] = qq;
        }
        // transpose-write raw bf16 featT (token-major), vectorized 16B stores
        int t_l = tid >> 3, cg = tid & 7;
        #pragma unroll
        for (int ii = 0; ii < 2; ii++) {
            int tl = ii * 32 + t_l;
            bf16x8 v;
            #pragma unroll
            for (int k = 0; k < 8; k++)
                v[k] = (short)f2bf(lds[cg * 8 + k][tl]);
            *(bf16x8*)(featT + (size_t)(b * HW_N + p0 + tl) * C_DIM + c0 + cg * 8) = v;
        }
    } else {                              // ---- wsel compaction + tokmap (32 blocks) ----
        if (tid < A_N) { lcnt[tid] = 0; lpos[tid] = 0; }
        __syncthreads();
        int t = (id - 3328) * 256 + tid;  // < 8192
        int b = t >> 12, p = t & (HW_N - 1);
        const float THR[9] = {1.0f/9.0f, 1.0f/7.0f, 0.2f, 1.0f/3.0f, 1.0f, 3.0f, 5.0f, 7.0f, 9.0f};
        int idxs[NANCH];
        #pragma unroll
        for (int na = 0; na < NANCH; na++) {
            float v = ar[(size_t)b * NANCH * HW_N + na * HW_N + p];
            int idx = 0;
            #pragma unroll
            for (int i = 0; i < 9; i++) idx += (v > THR[i]) ? 1 : 0;
            idxs[na] = idx;
        }
        int myA[NANCH], myC[NANCH], nmine = 0;
        #pragma unroll
        for (int j = 0; j < NANCH; j++) {
            bool first = true; int c3 = 0;
            #pragma unroll
            for (int k = 0; k < NANCH; k++) {
                if (idxs[k] == idxs[j]) { c3++; if (k < j) first = false; }
            }
            if (first) {
                myA[nmine] = idxs[j];
                myC[nmine] = c3;
                nmine++;
                atomicAdd(&lcnt[idxs[j]], 1);
            }
        }
        __syncthreads();
        if (tid < A_N) gbase[tid] = atomicAdd(&cnt[tid], lcnt[tid]);
        __syncthreads();
        for (int i = 0; i < NANCH; i++) {
            if (i < nmine) {
                int a2 = myA[i];
                int slot = atomicAdd(&lpos[a2], 1);
                int pos = gbase[a2] + slot;                 // global pos in adapter list
                tokw[a2 * NTOK + pos] = t;                  // row gather for gemm1c
                tokmap[t * 3 + i] = pos | (a2 << 13) | (myC[i] << 17);
            } else {
                tokmap[t * 3 + i] = 0;                      // weight 0 -> ignored
            }
        }
    }
}

// ======== 128x128 bf16 MFMA core, BK=64 (m97 single-buffer structure) ========
__device__ __forceinline__ void gemm_core_ptrs(
    const ushort_t* const ap[4], const ushort_t* const bp[4],
    int K, ushort_t* As, ushort_t* Bs, f32x4 acc[4][4]) {
    const int tid = threadIdx.x;
    const int lane = tid & 63;
    const int w = tid >> 6;
    const int wr = w >> 1, wc = w & 1;
    const int lrow = lane & 15;
    const int quad = lane >> 4;
    const int swzr = lrow & 7;

    #pragma unroll
    for (int i = 0; i < 4; i++)
        #pragma unroll
        for (int j = 0; j < 4; j++)
            #pragma unroll
            for (int e = 0; e < 4; e++) acc[i][j][e] = 0.f;

    for (int k0 = 0; k0 < K; k0 += 64) {
        __syncthreads();
        #pragma unroll
        for (int i = 0; i < 4; i++) {
            __builtin_amdgcn_global_load_lds(
                (__attribute__((address_space(1))) void*)(ap[i] + k0),
                (__attribute__((address_space(3))) void*)(As + (w * 32 + i * 8) * 64),
                16, 0, 0);
            __builtin_amdgcn_global_load_lds(
                (__attribute__((address_space(1))) void*)(bp[i] + k0),
                (__attribute__((address_space(3))) void*)(Bs + (w * 32 + i * 8) * 64),
                16, 0, 0);
        }
        __syncthreads();
        #pragma unroll
        for (int ks = 0; ks < 2; ks++) {
            const int cidx = ((ks * 4 + quad) ^ swzr) * 8;
            bf16x8 af[4], bfr[4];
            #pragma unroll
            for (int mt = 0; mt < 4; mt++)
                af[mt] = *(const bf16x8*)(As + (wr * 64 + mt * 16 + lrow) * 64 + cidx);
            #pragma unroll
            for (int nt = 0; nt < 4; nt++)
                bfr[nt] = *(const bf16x8*)(Bs + (wc * 64 + nt * 16 + lrow) * 64 + cidx);
            #pragma unroll
            for (int mt = 0; mt < 4; mt++)
                #pragma unroll
                for (int nt = 0; nt < 4; nt++)
                    acc[mt][nt] = __builtin_amdgcn_mfma_f32_16x16x32_bf16(af[mt], bfr[nt], acc[mt][nt], 0, 0, 0);
        }
    }
}

// ======== 128x128 core, BK=128 as two 64-wide panels per barrier pair ========
__device__ __forceinline__ void gemm_core_bk128(
    const ushort_t* const ap[4], const ushort_t* const bp[4],
    int K, ushort_t* As, ushort_t* Bs, f32x4 acc[4][4]) {
    const int tid = threadIdx.x;
    const int lane = tid & 63;
    const int w = tid >> 6;
    const int wr = w >> 1, wc = w & 1;
    const int lrow = lane & 15;
    const int quad = lane >> 4;
    const int swzr = lrow & 7;

    #pragma unroll
    for (int i = 0; i < 4; i++)
        #pragma unroll
        for (int j = 0; j < 4; j++)
            #pragma unroll
            for (int e = 0; e < 4; e++) acc[i][j][e] = 0.f;

    for (int k0 = 0; k0 < K; k0 += 128) {
        __syncthreads();
        #pragma unroll
        for (int p = 0; p < 2; p++) {
            #pragma unroll
            for (int i = 0; i < 4; i++) {
                __builtin_amdgcn_global_load_lds(
                    (__attribute__((address_space(1))) void*)(ap[i] + k0 + p * 64),
                    (__attribute__((address_space(3))) void*)(As + p * 8192 + (w * 32 + i * 8) * 64),
                    16, 0, 0);
                __builtin_amdgcn_global_load_lds(
                    (__attribute__((address_space(1))) void*)(bp[i] + k0 + p * 64),
                    (__attribute__((address_space(3))) void*)(Bs + p * 8192 + (w * 32 + i * 8) * 64),
                    16, 0, 0);
            }
        }
        __syncthreads();
        #pragma unroll
        for (int ks = 0; ks < 4; ks++) {
            const ushort_t* Ab = As + (ks >> 1) * 8192;
            const ushort_t* Bb = Bs + (ks >> 1) * 8192;
            const int cidx = (((ks & 1) * 4 + quad) ^ swzr) * 8;
            bf16x8 af[4], bfr[4];
            #pragma unroll
            for (int mt = 0; mt < 4; mt++)
                af[mt] = *(const bf16x8*)(Ab + (wr * 64 + mt * 16 + lrow) * 64 + cidx);
            #pragma unroll
            for (int nt = 0; nt < 4; nt++)
                bfr[nt] = *(const bf16x8*)(Bb + (wc * 64 + nt * 16 + lrow) * 64 + cidx);
            #pragma unroll
            for (int mt = 0; mt < 4; mt++)
                #pragma unroll
                for (int nt = 0; nt < 4; nt++)
                    acc[mt][nt] = __builtin_amdgcn_mfma_f32_16x16x32_bf16(af[mt], bfr[nt], acc[mt][nt], 0, 0, 0);
        }
    }
}

// GEMM1 (compacted M, raw-feat input, LN fused; partial-slot reduction in LDS):
// Hc[base_a + i][d] = gelu( r_t*(featT[tok_i] @ w1s[a] - m_t*cs1[a]) + bias1[a] )
__global__ __launch_bounds__(256) void gemm1c(const ushort_t* __restrict__ featT,
                                              const ushort_t* __restrict__ w1t,
                                              const float* __restrict__ bias1P,
                                              const float* __restrict__ cs1P,
                                              const float* __restrict__ sums,
                                              const int* __restrict__ tokw,
                                              const int* __restrict__ cnt,
                                              ushort_t* __restrict__ Hc) {
    int a = blockIdx.z;
    int mcount = cnt[a];
    int m0 = blockIdx.y * 128;
    if (m0 >= mcount) return;
    int n0 = blockIdx.x * 128;
    int base = 0;
    for (int a2 = 0; a2 < a; a2++) base += cnt[a2];

    __shared__ __align__(16) ushort_t As[2 * 128 * 64];
    __shared__ __align__(16) ushort_t Bs[2 * 128 * 64];
    __shared__ float rowM[128], rowR[128], colB[128], colC[128];

    int tid = threadIdx.x, lane = tid & 63, w = tid >> 6;
    int lrow8 = lane >> 3;
    int scol = ((lane & 7) ^ lrow8) * 8;
    int srowl = w * 32 + lrow8;

    const ushort_t* ap[4];
    const ushort_t* bp[4];
    #pragma unroll
    for (int i = 0; i < 4; i++) {
        int rt = tokw[a * NTOK + m0 + srowl + i * 8] & (NTOK - 1);
        ap[i] = featT + (size_t)rt * C_DIM + scol;
        bp[i] = w1t + ((size_t)a * CR + n0 + srowl + i * 8) * C_DIM + scol;
    }

    f32x4 acc[4][4];
    gemm_core_bk128(ap, bp, C_DIM, As, Bs, acc);

    // reduce the 16 partial slots per row (LN stats) and per col (bias/colsum)
    if (tid < 128) {
        int t = tokw[a * NTOK + m0 + tid] & (NTOK - 1);
        const f32x4* sp = (const f32x4*)(sums + (size_t)t * 32);
        f32x4 sv = sp[0] + sp[1] + sp[2] + sp[3];
        f32x4 sq = sp[4] + sp[5] + sp[6] + sp[7];
        float m = (sv[0] + sv[1] + sv[2] + sv[3]) * (1.f / C_DIM);
        float q = (sq[0] + sq[1] + sq[2] + sq[3]) * (1.f / C_DIM);
        rowM[tid] = m;
        rowR[tid] = rsqrtf(q - m * m + 1e-5f);
    } else {
        int j = tid - 128;
        size_t col = (size_t)(a * CR + n0 + j);
        const f32x4* bp4 = (const f32x4*)(bias1P + col * 16);
        const f32x4* cp4 = (const f32x4*)(cs1P + col * 16);
        f32x4 b4 = bp4[0] + bp4[1] + bp4[2] + bp4[3];
        f32x4 c4 = cp4[0] + cp4[1] + cp4[2] + cp4[3];
        colB[j] = b4[0] + b4[1] + b4[2] + b4[3];
        colC[j] = c4[0] + c4[1] + c4[2] + c4[3];
    }
    __syncthreads();

    int wr = w >> 1, wc = w & 1, lrow = lane & 15, quad = lane >> 4;
    float bi[4], cs[4];
    #pragma unroll
    for (int nt = 0; nt < 4; nt++) {
        int cl = wc * 64 + nt * 16 + lrow;
        bi[nt] = colB[cl];
        cs[nt] = colC[cl];
    }
    #pragma unroll
    for (int mt = 0; mt < 4; mt++)
        #pragma unroll
        for (int r = 0; r < 4; r++) {
            int rl = wr * 64 + mt * 16 + quad * 4 + r;
            int i_row = m0 + rl;
            bool live = i_row < mcount;
            float m = rowM[rl];
            float rn = rowR[rl];
            #pragma unroll
            for (int nt = 0; nt < 4; nt++) {
                int col = n0 + wc * 64 + nt * 16 + lrow;
                float v = rn * (acc[mt][nt][r] - m * cs[nt]) + bi[nt];
                if (live)
                    Hc[(size_t)(base + i_row) * CR + col] = f2bf(fast_gelu(v));
            }
        }
}

// GEMM2 (compacted, per-adapter K=256, BK=64): O[base_a + i][c] = Hc_a[i] @ w2[a]
__global__ __launch_bounds__(256) void gemm2c(const ushort_t* __restrict__ Hc,
                                              const ushort_t* __restrict__ w2t,
                                              const int* __restrict__ cnt,
                                              ushort_t* __restrict__ O) {
    int a = blockIdx.z;
    int mcount = cnt[a];
    int m0 = blockIdx.y * 128;
    if (m0 >= mcount) return;
    int n0 = blockIdx.x * 128;
    int base = 0;
    for (int a2 = 0; a2 < a; a2++) base += cnt[a2];

    __shared__ __align__(16) ushort_t As[128 * 64];
    __shared__ __align__(16) ushort_t Bs[128 * 64];

    int tid = threadIdx.x, lane = tid & 63, w = tid >> 6;
    int lrow8 = lane >> 3;
    int scol = ((lane & 7) ^ lrow8) * 8;
    int srowl = w * 32 + lrow8;

    const ushort_t* ap[4];
    const ushort_t* bp[4];
    #pragma unroll
    for (int i = 0; i < 4; i++) {
        ap[i] = Hc + (size_t)(base + m0 + srowl + i * 8) * CR + scol;
        bp[i] = w2t + (size_t)(n0 + srowl + i * 8) * KG2 + a * CR + scol;
    }

    f32x4 acc[4][4];
    gemm_core_ptrs(ap, bp, CR, As, Bs, acc);

    int wr = w >> 1, wc = w & 1, lrow = lane & 15, quad = lane >> 4;
    #pragma unroll
    for (int mt = 0; mt < 4; mt++)
        #pragma unroll
        for (int r = 0; r < 4; r++) {
            int i_row = m0 + wr * 64 + mt * 16 + quad * 4 + r;
            bool live = i_row < mcount;
            #pragma unroll
            for (int nt = 0; nt < 4; nt++) {
                int col = n0 + wc * 64 + nt * 16 + lrow;
                if (live)
                    O[(size_t)(base + i_row) * C_DIM + col] = f2bf(acc[mt][nt][r]);
            }
        }
}

// final gather: out[b][c][p] = feat + sum_j w_j * O[gpos_j(t)][c]
__global__ __launch_bounds__(256) void finalk2(const ushort_t* __restrict__ O,
                                               const int* __restrict__ tokmap,
                                               const int* __restrict__ cnt,
                                               const float* __restrict__ feat,
                                               float* __restrict__ out) {
    int p0 = blockIdx.x * 64, c0 = blockIdx.y * 64, b = blockIdx.z;
    __shared__ float lds[64][65];
    __shared__ int pbase[A_N];
    int tid = threadIdx.x, lo = tid & 63, hi = tid >> 6;
    if (tid < A_N) {
        int s = 0;
        for (int k = 0; k < tid; k++) s += cnt[k];
        pbase[tid] = s;
    }
    __syncthreads();
    int t_l = tid >> 3, cg = tid & 7;
    #pragma unroll
    for (int ii = 0; ii < 2; ii++) {
        int tl = ii * 32 + t_l;
        int t = b * HW_N + p0 + tl;
        float val8[8];
        #pragma unroll
        for (int k = 0; k < 8; k++) val8[k] = 0.f;
        #pragma unroll
        for (int j = 0; j < 3; j++) {
            int e = tokmap[t * 3 + j];
            float wv = (float)(e >> 17) * (1.0f / 3.0f);
            int a2 = (e >> 13) & 15;
            int row = pbase[a2] + (e & 8191);
            bf16x8 v = *(const bf16x8*)(O + (size_t)row * C_DIM + c0 + cg * 8);
            #pragma unroll
            for (int k = 0; k < 8; k++)
                val8[k] += wv * bf2f((ushort_t)v[k]);
        }
        #pragma unroll
        for (int k = 0; k < 8; k++)
            lds[tl][cg * 8 + k] = val8[k];      // 2-way bank alias max (free, m136)
    }
    __syncthreads();
    #pragma unroll
    for (int i = 0; i < 16; i++) {
        int c_l = i * 4 + hi;
        size_t o = ((size_t)b * C_DIM + c0 + c_l) * HW_N + p0 + lo;
        out[o] = lds[lo][c_l] + feat[o];
    }
}

// ---------------- launch ----------------
extern "C" void kernel_launch(void* const* d_in, const int* in_sizes, int n_in,
                              void* d_out, int out_size, void* d_ws, size_t ws_size,
                              hipStream_t stream) {
    (void)in_sizes; (void)n_in; (void)out_size; (void)ws_size;
    const float* feat = (const float*)d_in[0];
    const float* ar   = (const float*)d_in[1];
    const float* ln_s = (const float*)d_in[2];
    const float* ln_b = (const float*)d_in[3];
    const float* w1   = (const float*)d_in[4];
    const float* w2   = (const float*)d_in[5];
    float* out = (float*)d_out;
    char* ws = (char*)d_ws;

    // ---- cnt is the only zero-init target (40 B, zerok) ----
    int*      cnt    = (int*)(ws + 0);            // 64 B (padded)
    int*      tokmap = (int*)(ws + 64);           // 98,304   -> 98,368
    int*      tokw   = (int*)(ws + 98368);        // 327,680  -> 426,048
    ushort_t* w1t    = (ushort_t*)(ws + 426048);  // 5,242,880 -> 5,668,928
    ushort_t* w2t    = (ushort_t*)(ws + 5668928); // 5,242,880 -> 10,911,808
    ushort_t* featT  = (ushort_t*)(ws + 10911808);// 16,777,216 -> 27,689,024
    ushort_t* Hc     = (ushort_t*)(ws + 27689024);// 12,648,448 -> 40,337,472
    ushort_t* O      = (ushort_t*)(ws + 40337472);// 50,331,648 -> 90,669,120
    // partials live INSIDE O's region: written by prep, read by gemm1c, and O is
    // only written by gemm2c afterwards (disjoint lifetimes, stream-ordered).
    float*    sums   = (float*)O;                      // 8192*32*4 = 1,048,576
    float*    bias1P = (float*)((char*)O + 1048576);   // 2560*16*4 = 163,840
    float*    cs1P   = (float*)((char*)O + 1212416);   // 163,840 (ends 1,376,256)

    dim3 blk(256);
    zerok<<<dim3(1), dim3(64), 0, stream>>>(cnt);
    prep_all<<<dim3(3360), blk, 0, stream>>>(w1, w2, ln_s, ln_b, feat, ar,
                                             w1t, w2t, bias1P, cs1P, sums,
                                             cnt, tokw, tokmap, featT);
    gemm1c<<<dim3(2, 64, A_N), blk, 0, stream>>>(featT, w1t, bias1P, cs1P, sums,
                                                 tokw, cnt, Hc);
    gemm2c<<<dim3(8, 64, A_N), blk, 0, stream>>>(Hc, w2t, cnt, O);
    finalk2<<<dim3(64, 16, B_N), blk, 0, stream>>>(O, tokmap, cnt, feat, out);
}

// Round 11
// 95.517 us; speedup vs baseline: 1.2093x; 1.1036x over previous
//
#include <hip/hip_runtime.h>
#include <hip/hip_bf16.h>
#include <math.h>

#define C_DIM 1024
#define CR    256
#define A_N   10
#define NANCH 3
#define B_N   2
#define HW_N  4096
#define NTOK  (B_N*HW_N)   // 8192
#define KG2   (A_N*CR)     // 2560

typedef unsigned short ushort_t;
typedef __attribute__((ext_vector_type(4))) float f32x4;
typedef __attribute__((ext_vector_type(8))) short bf16x8;

__device__ __forceinline__ ushort_t f2bf(float x) {
    __hip_bfloat16 h = __float2bfloat16(x);
    return *reinterpret_cast<ushort_t*>(&h);
}
__device__ __forceinline__ float bf2f(ushort_t u) {
    return __uint_as_float(((unsigned)u) << 16);
}

// tanh-form GELU via sigmoid identity; |err| < ~1e-3 (below bf16 rounding)
__device__ __forceinline__ float fast_gelu(float x) {
    float t = x * x;
    float u = x * (-1.5957691216f - 0.0713548163f * t);
    float e = __expf(u);
    return x * __frcp_rn(1.0f + e);
}

// zero the atomic-target region (replaces hipMemsetAsync; cost-neutral, r8)
__global__ __launch_bounds__(256) void zerok(float* __restrict__ p, int n4) {
    int i = blockIdx.x * 256 + threadIdx.x;
    if (i < n4) {
        f32x4 z = {0.f, 0.f, 0.f, 0.f};
        *(f32x4*)(p + i * 4) = z;
    }
}

// ================= consolidated prep kernel =================
// blocks [0,640)    : w1t[a][d][c] = bf16(ln_scale*w1) transpose + bias1 partial
//                     (Σ ln_b*w1) + cs1 partial (Σ ln_s*w1) from the same LDS tile
// blocks [640,1280) : w2t transpose
// blocks [1280,3328): LN partial sums (atomic) + featT[t][c] = bf16(feat) transpose
// blocks [3328,3360): wsel compaction + tokmap
__global__ __launch_bounds__(256) void prep_all(
    const float* __restrict__ w1, const float* __restrict__ w2,
    const float* __restrict__ ln_s, const float* __restrict__ ln_b,
    const float* __restrict__ feat, const float* __restrict__ ar,
    ushort_t* __restrict__ w1t, ushort_t* __restrict__ w2t,
    float* __restrict__ bias1, float* __restrict__ cs1,
    float* __restrict__ sumv, float* __restrict__ sumq,
    int* __restrict__ cnt, int* __restrict__ tokw, int* __restrict__ tokmap,
    ushort_t* __restrict__ featT) {
    __shared__ float lds[64][65];
    __shared__ float bb[8][64];
    __shared__ int lcnt[A_N], lpos[A_N], gbase[A_N];
    int id = blockIdx.x, tid = threadIdx.x;
    int lo = tid & 63, hi = tid >> 6;

    if (id < 640) {                       // ---- prep_w1t + bias1 + cs1 ----
        int d0 = (id & 3) * 64, c0 = ((id >> 2) & 15) * 64, a = id >> 6;
        #pragma unroll
        for (int i = 0; i < 16; i++) {
            int c_l = i * 4 + hi;
            lds[c_l][lo] = w1[((size_t)a * C_DIM + c0 + c_l) * CR + d0 + lo];  // raw
        }
        __syncthreads();
        // partials: thread owns d=lo, sums 16 c's; bias (ln_b*w1) and colsum (ln_s*w1)
        {
            float s = 0.f, s2 = 0.f;
            #pragma unroll
            for (int cc = 0; cc < 16; cc++) {
                int c = hi * 16 + cc;
                float v = lds[c][lo];
                s  += v * ln_b[a * C_DIM + c0 + c];
                s2 += v * ln_s[a * C_DIM + c0 + c];
            }
            bb[hi][lo] = s;
            bb[hi + 4][lo] = s2;
        }
        // scaled transpose store
        float sc = ln_s[a * C_DIM + c0 + lo];
        #pragma unroll
        for (int i = 0; i < 16; i++) {
            int d_l = i * 4 + hi;
            w1t[((size_t)a * CR + d0 + d_l) * C_DIM + c0 + lo] = f2bf(lds[lo][d_l] * sc);
        }
        __syncthreads();
        if (hi == 0)
            atomicAdd(&bias1[a * CR + d0 + lo], bb[0][lo] + bb[1][lo] + bb[2][lo] + bb[3][lo]);
        else if (hi == 1)
            atomicAdd(&cs1[a * CR + d0 + lo], bb[4][lo] + bb[5][lo] + bb[6][lo] + bb[7][lo]);
    } else if (id < 1280) {               // ---- prep_w2t ----
        int id2 = id - 640;
        int k0 = (id2 % 40) * 64, c0 = (id2 / 40) * 64;
        #pragma unroll
        for (int i = 0; i < 16; i++) {
            int k_l = i * 4 + hi;
            lds[k_l][lo] = w2[((size_t)k0 + k_l) * C_DIM + c0 + lo];
        }
        __syncthreads();
        #pragma unroll
        for (int i = 0; i < 16; i++) {
            int c_l = i * 4 + hi;
            w2t[((size_t)c0 + c_l) * KG2 + k0 + lo] = f2bf(lds[lo][c_l]);
        }
    } else if (id < 3328) {               // ---- ln partial sums + featT transpose ----
        int id2 = id - 1280;
        int p0 = (id2 & 63) * 64, c0idx = (id2 >> 6) & 15, b = id2 >> 10;
        int c0 = c0idx * 64;
        #pragma unroll
        for (int i = 0; i < 16; i++) {
            int c_l = i * 4 + hi;
            lds[c_l][lo] = feat[((size_t)b * C_DIM + c0 + c_l) * HW_N + p0 + lo];
        }
        __syncthreads();
        // partial sums over this block's 64 c's, per p=lo
        {
            float s = 0.f, s2 = 0.f;
            #pragma unroll
            for (int c = hi; c < 64; c += 4) {
                float v = lds[c][lo];
                s += v; s2 += v * v;
            }
            bb[hi][lo] = s; bb[hi + 4][lo] = s2;
        }
        __syncthreads();
        if (tid < 64) {
            float ss = bb[0][tid] + bb[1][tid] + bb[2][tid] + bb[3][tid];
            float qq = bb[4][tid] + bb[5][tid] + bb[6][tid] + bb[7][tid];
            int t = b * HW_N + p0 + tid;
            atomicAdd(&sumv[t], ss);
            atomicAdd(&sumq[t], qq);
        }
        // transpose-write raw bf16 featT (token-major), vectorized 16B stores
        int t_l = tid >> 3, cg = tid & 7;
        #pragma unroll
        for (int ii = 0; ii < 2; ii++) {
            int tl = ii * 32 + t_l;
            bf16x8 v;
            #pragma unroll
            for (int k = 0; k < 8; k++)
                v[k] = (short)f2bf(lds[cg * 8 + k][tl]);
            *(bf16x8*)(featT + (size_t)(b * HW_N + p0 + tl) * C_DIM + c0 + cg * 8) = v;
        }
    } else {                              // ---- wsel compaction + tokmap ----
        if (tid < A_N) { lcnt[tid] = 0; lpos[tid] = 0; }
        __syncthreads();
        int t = (id - 3328) * 256 + tid;  // < 8192
        int b = t >> 12, p = t & (HW_N - 1);
        const float THR[9] = {1.0f/9.0f, 1.0f/7.0f, 0.2f, 1.0f/3.0f, 1.0f, 3.0f, 5.0f, 7.0f, 9.0f};
        int idxs[NANCH];
        #pragma unroll
        for (int na = 0; na < NANCH; na++) {
            float v = ar[(size_t)b * NANCH * HW_N + na * HW_N + p];
            int idx = 0;
            #pragma unroll
            for (int i = 0; i < 9; i++) idx += (v > THR[i]) ? 1 : 0;
            idxs[na] = idx;
        }
        int myA[NANCH], myC[NANCH], nmine = 0;
        #pragma unroll
        for (int j = 0; j < NANCH; j++) {
            bool first = true; int c3 = 0;
            #pragma unroll
            for (int k = 0; k < NANCH; k++) {
                if (idxs[k] == idxs[j]) { c3++; if (k < j) first = false; }
            }
            if (first) {
                myA[nmine] = idxs[j];
                myC[nmine] = c3;
                nmine++;
                atomicAdd(&lcnt[idxs[j]], 1);
            }
        }
        __syncthreads();
        if (tid < A_N) gbase[tid] = atomicAdd(&cnt[tid], lcnt[tid]);
        __syncthreads();
        for (int i = 0; i < NANCH; i++) {
            if (i < nmine) {
                int a2 = myA[i];
                int slot = atomicAdd(&lpos[a2], 1);
                int pos = gbase[a2] + slot;                 // global pos in adapter list
                tokw[a2 * NTOK + pos] = t;                  // row gather for gemm1c
                tokmap[t * 3 + i] = pos | (a2 << 13) | (myC[i] << 17);
            } else {
                tokmap[t * 3 + i] = 0;                      // weight 0 -> ignored
            }
        }
    }
}

// ======== 128x128 bf16 MFMA core, BK=64 (m97 single-buffer structure) ========
__device__ __forceinline__ void gemm_core_ptrs(
    const ushort_t* const ap[4], const ushort_t* const bp[4],
    int K, ushort_t* As, ushort_t* Bs, f32x4 acc[4][4]) {
    const int tid = threadIdx.x;
    const int lane = tid & 63;
    const int w = tid >> 6;
    const int wr = w >> 1, wc = w & 1;
    const int lrow = lane & 15;
    const int quad = lane >> 4;
    const int swzr = lrow & 7;

    #pragma unroll
    for (int i = 0; i < 4; i++)
        #pragma unroll
        for (int j = 0; j < 4; j++)
            #pragma unroll
            for (int e = 0; e < 4; e++) acc[i][j][e] = 0.f;

    for (int k0 = 0; k0 < K; k0 += 64) {
        __syncthreads();
        #pragma unroll
        for (int i = 0; i < 4; i++) {
            __builtin_amdgcn_global_load_lds(
                (__attribute__((address_space(1))) void*)(ap[i] + k0),
                (__attribute__((address_space(3))) void*)(As + (w * 32 + i * 8) * 64),
                16, 0, 0);
            __builtin_amdgcn_global_load_lds(
                (__attribute__((address_space(1))) void*)(bp[i] + k0),
                (__attribute__((address_space(3))) void*)(Bs + (w * 32 + i * 8) * 64),
                16, 0, 0);
        }
        __syncthreads();
        #pragma unroll
        for (int ks = 0; ks < 2; ks++) {
            const int cidx = ((ks * 4 + quad) ^ swzr) * 8;
            bf16x8 af[4], bfr[4];
            #pragma unroll
            for (int mt = 0; mt < 4; mt++)
                af[mt] = *(const bf16x8*)(As + (wr * 64 + mt * 16 + lrow) * 64 + cidx);
            #pragma unroll
            for (int nt = 0; nt < 4; nt++)
                bfr[nt] = *(const bf16x8*)(Bs + (wc * 64 + nt * 16 + lrow) * 64 + cidx);
            #pragma unroll
            for (int mt = 0; mt < 4; mt++)
                #pragma unroll
                for (int nt = 0; nt < 4; nt++)
                    acc[mt][nt] = __builtin_amdgcn_mfma_f32_16x16x32_bf16(af[mt], bfr[nt], acc[mt][nt], 0, 0, 0);
        }
    }
}

// ======== 128x128 core, BK=128 as two 64-wide panels per barrier pair ========
// Halves barrier/drain count for K-deep GEMMs in the co-residency-starved regime
// (gemm1c: ~1.3 blocks/CU, so m132's occupancy objection doesn't apply).
__device__ __forceinline__ void gemm_core_bk128(
    const ushort_t* const ap[4], const ushort_t* const bp[4],
    int K, ushort_t* As, ushort_t* Bs, f32x4 acc[4][4]) {
    const int tid = threadIdx.x;
    const int lane = tid & 63;
    const int w = tid >> 6;
    const int wr = w >> 1, wc = w & 1;
    const int lrow = lane & 15;
    const int quad = lane >> 4;
    const int swzr = lrow & 7;

    #pragma unroll
    for (int i = 0; i < 4; i++)
        #pragma unroll
        for (int j = 0; j < 4; j++)
            #pragma unroll
            for (int e = 0; e < 4; e++) acc[i][j][e] = 0.f;

    for (int k0 = 0; k0 < K; k0 += 128) {
        __syncthreads();
        #pragma unroll
        for (int p = 0; p < 2; p++) {
            #pragma unroll
            for (int i = 0; i < 4; i++) {
                __builtin_amdgcn_global_load_lds(
                    (__attribute__((address_space(1))) void*)(ap[i] + k0 + p * 64),
                    (__attribute__((address_space(3))) void*)(As + p * 8192 + (w * 32 + i * 8) * 64),
                    16, 0, 0);
                __builtin_amdgcn_global_load_lds(
                    (__attribute__((address_space(1))) void*)(bp[i] + k0 + p * 64),
                    (__attribute__((address_space(3))) void*)(Bs + p * 8192 + (w * 32 + i * 8) * 64),
                    16, 0, 0);
            }
        }
        __syncthreads();
        #pragma unroll
        for (int ks = 0; ks < 4; ks++) {
            const ushort_t* Ab = As + (ks >> 1) * 8192;
            const ushort_t* Bb = Bs + (ks >> 1) * 8192;
            const int cidx = (((ks & 1) * 4 + quad) ^ swzr) * 8;
            bf16x8 af[4], bfr[4];
            #pragma unroll
            for (int mt = 0; mt < 4; mt++)
                af[mt] = *(const bf16x8*)(Ab + (wr * 64 + mt * 16 + lrow) * 64 + cidx);
            #pragma unroll
            for (int nt = 0; nt < 4; nt++)
                bfr[nt] = *(const bf16x8*)(Bb + (wc * 64 + nt * 16 + lrow) * 64 + cidx);
            #pragma unroll
            for (int mt = 0; mt < 4; mt++)
                #pragma unroll
                for (int nt = 0; nt < 4; nt++)
                    acc[mt][nt] = __builtin_amdgcn_mfma_f32_16x16x32_bf16(af[mt], bfr[nt], acc[mt][nt], 0, 0, 0);
        }
    }
}

// GEMM1 (compacted M, raw-feat input, LN fused into epilogue, BK=128):
// Hc[base_a + i][d] = gelu( r_t*(featT[tok_i] @ w1s[a] - m_t*cs1[a]) + bias1[a] )
__global__ __launch_bounds__(256) void gemm1c(const ushort_t* __restrict__ featT,
                                              const ushort_t* __restrict__ w1t,
                                              const float* __restrict__ bias1,
                                              const float* __restrict__ cs1,
                                              const float* __restrict__ sumv,
                                              const float* __restrict__ sumq,
                                              const int* __restrict__ tokw,
                                              const int* __restrict__ cnt,
                                              ushort_t* __restrict__ Hc) {
    int a = blockIdx.z;
    int mcount = cnt[a];
    int m0 = blockIdx.y * 128;
    if (m0 >= mcount) return;
    int n0 = blockIdx.x * 128;
    int base = 0;
    for (int a2 = 0; a2 < a; a2++) base += cnt[a2];

    __shared__ __align__(16) ushort_t As[2 * 128 * 64];
    __shared__ __align__(16) ushort_t Bs[2 * 128 * 64];

    int tid = threadIdx.x, lane = tid & 63, w = tid >> 6;
    int lrow8 = lane >> 3;
    int scol = ((lane & 7) ^ lrow8) * 8;
    int srowl = w * 32 + lrow8;

    const ushort_t* ap[4];
    const ushort_t* bp[4];
    #pragma unroll
    for (int i = 0; i < 4; i++) {
        int rt = tokw[a * NTOK + m0 + srowl + i * 8] & (NTOK - 1);
        ap[i] = featT + (size_t)rt * C_DIM + scol;
        bp[i] = w1t + ((size_t)a * CR + n0 + srowl + i * 8) * C_DIM + scol;
    }

    f32x4 acc[4][4];
    gemm_core_bk128(ap, bp, C_DIM, As, Bs, acc);

    int wr = w >> 1, wc = w & 1, lrow = lane & 15, quad = lane >> 4;
    float bi[4], cs[4];
    #pragma unroll
    for (int nt = 0; nt < 4; nt++) {
        int col = a * CR + n0 + wc * 64 + nt * 16 + lrow;
        bi[nt] = bias1[col];
        cs[nt] = cs1[col];
    }
    #pragma unroll
    for (int mt = 0; mt < 4; mt++)
        #pragma unroll
        for (int r = 0; r < 4; r++) {
            int i_row = m0 + wr * 64 + mt * 16 + quad * 4 + r;
            bool live = i_row < mcount;
            int t = tokw[a * NTOK + i_row] & (NTOK - 1);
            float m = sumv[t] * (1.f / C_DIM);
            float q = sumq[t] * (1.f / C_DIM);
            float rn = rsqrtf(q - m * m + 1e-5f);
            #pragma unroll
            for (int nt = 0; nt < 4; nt++) {
                int col = n0 + wc * 64 + nt * 16 + lrow;
                float v = rn * (acc[mt][nt][r] - m * cs[nt]) + bi[nt];
                if (live)
                    Hc[(size_t)(base + i_row) * CR + col] = f2bf(fast_gelu(v));
            }
        }
}

// GEMM2 (compacted, per-adapter K=256, BK=64): O[base_a + i][c] = Hc_a[i] @ w2[a]
__global__ __launch_bounds__(256) void gemm2c(const ushort_t* __restrict__ Hc,
                                              const ushort_t* __restrict__ w2t,
                                              const int* __restrict__ cnt,
                                              ushort_t* __restrict__ O) {
    int a = blockIdx.z;
    int mcount = cnt[a];
    int m0 = blockIdx.y * 128;
    if (m0 >= mcount) return;
    int n0 = blockIdx.x * 128;
    int base = 0;
    for (int a2 = 0; a2 < a; a2++) base += cnt[a2];

    __shared__ __align__(16) ushort_t As[128 * 64];
    __shared__ __align__(16) ushort_t Bs[128 * 64];

    int tid = threadIdx.x, lane = tid & 63, w = tid >> 6;
    int lrow8 = lane >> 3;
    int scol = ((lane & 7) ^ lrow8) * 8;
    int srowl = w * 32 + lrow8;

    const ushort_t* ap[4];
    const ushort_t* bp[4];
    #pragma unroll
    for (int i = 0; i < 4; i++) {
        ap[i] = Hc + (size_t)(base + m0 + srowl + i * 8) * CR + scol;
        bp[i] = w2t + (size_t)(n0 + srowl + i * 8) * KG2 + a * CR + scol;
    }

    f32x4 acc[4][4];
    gemm_core_ptrs(ap, bp, CR, As, Bs, acc);

    int wr = w >> 1, wc = w & 1, lrow = lane & 15, quad = lane >> 4;
    #pragma unroll
    for (int mt = 0; mt < 4; mt++)
        #pragma unroll
        for (int r = 0; r < 4; r++) {
            int i_row = m0 + wr * 64 + mt * 16 + quad * 4 + r;
            bool live = i_row < mcount;
            #pragma unroll
            for (int nt = 0; nt < 4; nt++) {
                int col = n0 + wc * 64 + nt * 16 + lrow;
                if (live)
                    O[(size_t)(base + i_row) * C_DIM + col] = f2bf(acc[mt][nt][r]);
            }
        }
}

// final gather: out[b][c][p] = feat + sum_j w_j * O[gpos_j(t)][c]
// O-read vectorized: 8-lane group per token, bf16x8 (16B) loads.
__global__ __launch_bounds__(256) void finalk2(const ushort_t* __restrict__ O,
                                               const int* __restrict__ tokmap,
                                               const int* __restrict__ cnt,
                                               const float* __restrict__ feat,
                                               float* __restrict__ out) {
    int p0 = blockIdx.x * 64, c0 = blockIdx.y * 64, b = blockIdx.z;
    __shared__ float lds[64][65];
    __shared__ int pbase[A_N];
    int tid = threadIdx.x, lo = tid & 63, hi = tid >> 6;
    if (tid < A_N) {
        int s = 0;
        for (int k = 0; k < tid; k++) s += cnt[k];
        pbase[tid] = s;
    }
    __syncthreads();
    int t_l = tid >> 3, cg = tid & 7;
    #pragma unroll
    for (int ii = 0; ii < 2; ii++) {
        int tl = ii * 32 + t_l;
        int t = b * HW_N + p0 + tl;
        float val8[8];
        #pragma unroll
        for (int k = 0; k < 8; k++) val8[k] = 0.f;
        #pragma unroll
        for (int j = 0; j < 3; j++) {
            int e = tokmap[t * 3 + j];
            float wv = (float)(e >> 17) * (1.0f / 3.0f);
            int a2 = (e >> 13) & 15;
            int row = pbase[a2] + (e & 8191);
            bf16x8 v = *(const bf16x8*)(O + (size_t)row * C_DIM + c0 + cg * 8);
            #pragma unroll
            for (int k = 0; k < 8; k++)
                val8[k] += wv * bf2f((ushort_t)v[k]);
        }
        #pragma unroll
        for (int k = 0; k < 8; k++)
            lds[tl][cg * 8 + k] = val8[k];      // 2-way bank alias max (free, m136)
    }
    __syncthreads();
    #pragma unroll
    for (int i = 0; i < 16; i++) {
        int c_l = i * 4 + hi;
        size_t o = ((size_t)b * C_DIM + c0 + c_l) * HW_N + p0 + lo;
        out[o] = lds[lo][c_l] + feat[o];
    }
}

// ---------------- launch ----------------
extern "C" void kernel_launch(void* const* d_in, const int* in_sizes, int n_in,
                              void* d_out, int out_size, void* d_ws, size_t ws_size,
                              hipStream_t stream) {
    (void)in_sizes; (void)n_in; (void)out_size; (void)ws_size;
    const float* feat = (const float*)d_in[0];
    const float* ar   = (const float*)d_in[1];
    const float* ln_s = (const float*)d_in[2];
    const float* ln_b = (const float*)d_in[3];
    const float* w1   = (const float*)d_in[4];
    const float* w2   = (const float*)d_in[5];
    float* out = (float*)d_out;
    char* ws = (char*)d_ws;

    // ---- zero-init region (zeroed by zerok kernel: atomic targets only) ----
    float*    bias1  = (float*)(ws + 0);          // 10,240
    float*    cs1    = (float*)(ws + 10240);      // 10,240 -> 20,480
    int*      cnt    = (int*)(ws + 20480);        // 40 (pad to 20,736)
    float*    sumv   = (float*)(ws + 20736);      // 32,768 -> 53,504
    float*    sumq   = (float*)(ws + 53504);      // 32,768 -> 86,272
    const size_t ZERO_BYTES = 86272;              // /16 = 5392 f32x4
    // ---- uninitialized region ----
    int*      tokmap = (int*)(ws + 86272);        // 98,304   -> 184,576
    int*      tokw   = (int*)(ws + 184576);       // 327,680  -> 512,256
    ushort_t* w1t    = (ushort_t*)(ws + 512256);  // 5,242,880 -> 5,755,136
    ushort_t* w2t    = (ushort_t*)(ws + 5755136); // 5,242,880 -> 10,998,016
    ushort_t* featT  = (ushort_t*)(ws + 10998016);// 16,777,216 -> 27,775,232
    ushort_t* Hc     = (ushort_t*)(ws + 27775232);// 12,648,448 -> 40,423,680
    ushort_t* O      = (ushort_t*)(ws + 40423680);// 50,331,648 -> 90,755,328

    dim3 blk(256);
    zerok<<<dim3((int)(ZERO_BYTES / 16 + 255) / 256), blk, 0, stream>>>((float*)ws, (int)(ZERO_BYTES / 16));
    prep_all<<<dim3(3360), blk, 0, stream>>>(w1, w2, ln_s, ln_b, feat, ar,
                                             w1t, w2t, bias1, cs1, sumv, sumq,
                                             cnt, tokw, tokmap, featT);
    gemm1c<<<dim3(2, 64, A_N), blk, 0, stream>>>(featT, w1t, bias1, cs1, sumv, sumq,
                                                 tokw, cnt, Hc);
    gemm2c<<<dim3(8, 64, A_N), blk, 0, stream>>>(Hc, w2t, cnt, O);
    finalk2<<<dim3(64, 16, B_N), blk, 0, stream>>>(O, tokmap, cnt, feat, out);
}

// Round 12
// 94.977 us; speedup vs baseline: 1.2162x; 1.0057x over previous
//
#include <hip/hip_runtime.h>
#include <hip/hip_bf16.h>
#include <math.h>

#define C_DIM 1024
#define CR    256
#define A_N   10
#define NANCH 3
#define B_N   2
#define HW_N  4096
#define NTOK  (B_N*HW_N)   // 8192
#define KG2   (A_N*CR)     // 2560

typedef unsigned short ushort_t;
typedef __attribute__((ext_vector_type(4))) float f32x4;
typedef __attribute__((ext_vector_type(8))) short bf16x8;

__device__ __forceinline__ ushort_t f2bf(float x) {
    __hip_bfloat16 h = __float2bfloat16(x);
    return *reinterpret_cast<ushort_t*>(&h);
}
__device__ __forceinline__ float bf2f(ushort_t u) {
    return __uint_as_float(((unsigned)u) << 16);
}

// tanh-form GELU via sigmoid identity; |err| < ~1e-3 (below bf16 rounding)
__device__ __forceinline__ float fast_gelu(float x) {
    float t = x * x;
    float u = x * (-1.5957691216f - 0.0713548163f * t);
    float e = __expf(u);
    return x * __frcp_rn(1.0f + e);
}

// zero the atomic-target region (replaces hipMemsetAsync; cost-neutral, r8)
__global__ __launch_bounds__(256) void zerok(float* __restrict__ p, int n4) {
    int i = blockIdx.x * 256 + threadIdx.x;
    if (i < n4) {
        f32x4 z = {0.f, 0.f, 0.f, 0.f};
        *(f32x4*)(p + i * 4) = z;
    }
}

// ================= consolidated prep kernel =================
// blocks [0,640)    : w1t[a][d][c] = bf16(ln_scale*w1) transpose + bias1 partial
//                     (Σ ln_b*w1) + cs1 partial (Σ ln_s*w1) from the same LDS tile
// blocks [640,1280) : w2t transpose
// blocks [1280,3328): LN partial sums (atomic) + featT[t][c] = bf16(feat) transpose
// blocks [3328,3360): wsel compaction + tokmap
// r12: w1t/w2t stores vectorized to bf16x8 (were scalar 2B; G13 — last scalar stores)
__global__ __launch_bounds__(256) void prep_all(
    const float* __restrict__ w1, const float* __restrict__ w2,
    const float* __restrict__ ln_s, const float* __restrict__ ln_b,
    const float* __restrict__ feat, const float* __restrict__ ar,
    ushort_t* __restrict__ w1t, ushort_t* __restrict__ w2t,
    float* __restrict__ bias1, float* __restrict__ cs1,
    float* __restrict__ sumv, float* __restrict__ sumq,
    int* __restrict__ cnt, int* __restrict__ tokw, int* __restrict__ tokmap,
    ushort_t* __restrict__ featT) {
    __shared__ float lds[64][65];
    __shared__ float bb[8][64];
    __shared__ int lcnt[A_N], lpos[A_N], gbase[A_N];
    int id = blockIdx.x, tid = threadIdx.x;
    int lo = tid & 63, hi = tid >> 6;

    if (id < 640) {                       // ---- prep_w1t + bias1 + cs1 ----
        int d0 = (id & 3) * 64, c0 = ((id >> 2) & 15) * 64, a = id >> 6;
        #pragma unroll
        for (int i = 0; i < 16; i++) {
            int c_l = i * 4 + hi;
            lds[c_l][lo] = w1[((size_t)a * C_DIM + c0 + c_l) * CR + d0 + lo];  // raw
        }
        __syncthreads();
        // partials: thread owns d=lo, sums 16 c's; bias (ln_b*w1) and colsum (ln_s*w1)
        {
            float s = 0.f, s2 = 0.f;
            #pragma unroll
            for (int cc = 0; cc < 16; cc++) {
                int c = hi * 16 + cc;
                float v = lds[c][lo];
                s  += v * ln_b[a * C_DIM + c0 + c];
                s2 += v * ln_s[a * C_DIM + c0 + c];
            }
            bb[hi][lo] = s;
            bb[hi + 4][lo] = s2;
        }
        // scaled transpose store, vectorized: 8-lane group packs 8 contiguous c's
        {
            int d_l8 = tid >> 3, cg = tid & 7;
            #pragma unroll
            for (int ii = 0; ii < 2; ii++) {
                int d_l = ii * 32 + d_l8;
                bf16x8 v;
                #pragma unroll
                for (int k = 0; k < 8; k++) {
                    int c = cg * 8 + k;
                    v[k] = (short)f2bf(lds[c][d_l] * ln_s[a * C_DIM + c0 + c]);
                }
                *(bf16x8*)(w1t + ((size_t)a * CR + d0 + d_l) * C_DIM + c0 + cg * 8) = v;
            }
        }
        __syncthreads();
        if (hi == 0)
            atomicAdd(&bias1[a * CR + d0 + lo], bb[0][lo] + bb[1][lo] + bb[2][lo] + bb[3][lo]);
        else if (hi == 1)
            atomicAdd(&cs1[a * CR + d0 + lo], bb[4][lo] + bb[5][lo] + bb[6][lo] + bb[7][lo]);
    } else if (id < 1280) {               // ---- prep_w2t ----
        int id2 = id - 640;
        int k0 = (id2 % 40) * 64, c0 = (id2 / 40) * 64;
        #pragma unroll
        for (int i = 0; i < 16; i++) {
            int k_l = i * 4 + hi;
            lds[k_l][lo] = w2[((size_t)k0 + k_l) * C_DIM + c0 + lo];
        }
        __syncthreads();
        // transpose store, vectorized: 8-lane group packs 8 contiguous k's
        {
            int c_l8 = tid >> 3, kg = tid & 7;
            #pragma unroll
            for (int ii = 0; ii < 2; ii++) {
                int c_l = ii * 32 + c_l8;
                bf16x8 v;
                #pragma unroll
                for (int k = 0; k < 8; k++)
                    v[k] = (short)f2bf(lds[kg * 8 + k][c_l]);
                *(bf16x8*)(w2t + ((size_t)c0 + c_l) * KG2 + k0 + kg * 8) = v;
            }
        }
    } else if (id < 3328) {               // ---- ln partial sums + featT transpose ----
        int id2 = id - 1280;
        int p0 = (id2 & 63) * 64, c0idx = (id2 >> 6) & 15, b = id2 >> 10;
        int c0 = c0idx * 64;
        #pragma unroll
        for (int i = 0; i < 16; i++) {
            int c_l = i * 4 + hi;
            lds[c_l][lo] = feat[((size_t)b * C_DIM + c0 + c_l) * HW_N + p0 + lo];
        }
        __syncthreads();
        // partial sums over this block's 64 c's, per p=lo
        {
            float s = 0.f, s2 = 0.f;
            #pragma unroll
            for (int c = hi; c < 64; c += 4) {
                float v = lds[c][lo];
                s += v; s2 += v * v;
            }
            bb[hi][lo] = s; bb[hi + 4][lo] = s2;
        }
        __syncthreads();
        if (tid < 64) {
            float ss = bb[0][tid] + bb[1][tid] + bb[2][tid] + bb[3][tid];
            float qq = bb[4][tid] + bb[5][tid] + bb[6][tid] + bb[7][tid];
            int t = b * HW_N + p0 + tid;
            atomicAdd(&sumv[t], ss);
            atomicAdd(&sumq[t], qq);
        }
        // transpose-write raw bf16 featT (token-major), vectorized 16B stores
        int t_l = tid >> 3, cg = tid & 7;
        #pragma unroll
        for (int ii = 0; ii < 2; ii++) {
            int tl = ii * 32 + t_l;
            bf16x8 v;
            #pragma unroll
            for (int k = 0; k < 8; k++)
                v[k] = (short)f2bf(lds[cg * 8 + k][tl]);
            *(bf16x8*)(featT + (size_t)(b * HW_N + p0 + tl) * C_DIM + c0 + cg * 8) = v;
        }
    } else {                              // ---- wsel compaction + tokmap ----
        if (tid < A_N) { lcnt[tid] = 0; lpos[tid] = 0; }
        __syncthreads();
        int t = (id - 3328) * 256 + tid;  // < 8192
        int b = t >> 12, p = t & (HW_N - 1);
        const float THR[9] = {1.0f/9.0f, 1.0f/7.0f, 0.2f, 1.0f/3.0f, 1.0f, 3.0f, 5.0f, 7.0f, 9.0f};
        int idxs[NANCH];
        #pragma unroll
        for (int na = 0; na < NANCH; na++) {
            float v = ar[(size_t)b * NANCH * HW_N + na * HW_N + p];
            int idx = 0;
            #pragma unroll
            for (int i = 0; i < 9; i++) idx += (v > THR[i]) ? 1 : 0;
            idxs[na] = idx;
        }
        int myA[NANCH], myC[NANCH], nmine = 0;
        #pragma unroll
        for (int j = 0; j < NANCH; j++) {
            bool first = true; int c3 = 0;
            #pragma unroll
            for (int k = 0; k < NANCH; k++) {
                if (idxs[k] == idxs[j]) { c3++; if (k < j) first = false; }
            }
            if (first) {
                myA[nmine] = idxs[j];
                myC[nmine] = c3;
                nmine++;
                atomicAdd(&lcnt[idxs[j]], 1);
            }
        }
        __syncthreads();
        if (tid < A_N) gbase[tid] = atomicAdd(&cnt[tid], lcnt[tid]);
        __syncthreads();
        for (int i = 0; i < NANCH; i++) {
            if (i < nmine) {
                int a2 = myA[i];
                int slot = atomicAdd(&lpos[a2], 1);
                int pos = gbase[a2] + slot;                 // global pos in adapter list
                tokw[a2 * NTOK + pos] = t;                  // row gather for gemm1c
                tokmap[t * 3 + i] = pos | (a2 << 13) | (myC[i] << 17);
            } else {
                tokmap[t * 3 + i] = 0;                      // weight 0 -> ignored
            }
        }
    }
}

// ======== 128x128 bf16 MFMA core, BK=64 (m97 single-buffer structure) ========
__device__ __forceinline__ void gemm_core_ptrs(
    const ushort_t* const ap[4], const ushort_t* const bp[4],
    int K, ushort_t* As, ushort_t* Bs, f32x4 acc[4][4]) {
    const int tid = threadIdx.x;
    const int lane = tid & 63;
    const int w = tid >> 6;
    const int wr = w >> 1, wc = w & 1;
    const int lrow = lane & 15;
    const int quad = lane >> 4;
    const int swzr = lrow & 7;

    #pragma unroll
    for (int i = 0; i < 4; i++)
        #pragma unroll
        for (int j = 0; j < 4; j++)
            #pragma unroll
            for (int e = 0; e < 4; e++) acc[i][j][e] = 0.f;

    for (int k0 = 0; k0 < K; k0 += 64) {
        __syncthreads();
        #pragma unroll
        for (int i = 0; i < 4; i++) {
            __builtin_amdgcn_global_load_lds(
                (__attribute__((address_space(1))) void*)(ap[i] + k0),
                (__attribute__((address_space(3))) void*)(As + (w * 32 + i * 8) * 64),
                16, 0, 0);
            __builtin_amdgcn_global_load_lds(
                (__attribute__((address_space(1))) void*)(bp[i] + k0),
                (__attribute__((address_space(3))) void*)(Bs + (w * 32 + i * 8) * 64),
                16, 0, 0);
        }
        __syncthreads();
        #pragma unroll
        for (int ks = 0; ks < 2; ks++) {
            const int cidx = ((ks * 4 + quad) ^ swzr) * 8;
            bf16x8 af[4], bfr[4];
            #pragma unroll
            for (int mt = 0; mt < 4; mt++)
                af[mt] = *(const bf16x8*)(As + (wr * 64 + mt * 16 + lrow) * 64 + cidx);
            #pragma unroll
            for (int nt = 0; nt < 4; nt++)
                bfr[nt] = *(const bf16x8*)(Bs + (wc * 64 + nt * 16 + lrow) * 64 + cidx);
            #pragma unroll
            for (int mt = 0; mt < 4; mt++)
                #pragma unroll
                for (int nt = 0; nt < 4; nt++)
                    acc[mt][nt] = __builtin_amdgcn_mfma_f32_16x16x32_bf16(af[mt], bfr[nt], acc[mt][nt], 0, 0, 0);
        }
    }
}

// ======== 128x128 core, BK=128 as two 64-wide panels per barrier pair ========
// Halves barrier/drain count for K-deep GEMMs in the co-residency-starved regime
// (gemm1c: ~1.3 blocks/CU, so m132's occupancy objection doesn't apply).
__device__ __forceinline__ void gemm_core_bk128(
    const ushort_t* const ap[4], const ushort_t* const bp[4],
    int K, ushort_t* As, ushort_t* Bs, f32x4 acc[4][4]) {
    const int tid = threadIdx.x;
    const int lane = tid & 63;
    const int w = tid >> 6;
    const int wr = w >> 1, wc = w & 1;
    const int lrow = lane & 15;
    const int quad = lane >> 4;
    const int swzr = lrow & 7;

    #pragma unroll
    for (int i = 0; i < 4; i++)
        #pragma unroll
        for (int j = 0; j < 4; j++)
            #pragma unroll
            for (int e = 0; e < 4; e++) acc[i][j][e] = 0.f;

    for (int k0 = 0; k0 < K; k0 += 128) {
        __syncthreads();
        #pragma unroll
        for (int p = 0; p < 2; p++) {
            #pragma unroll
            for (int i = 0; i < 4; i++) {
                __builtin_amdgcn_global_load_lds(
                    (__attribute__((address_space(1))) void*)(ap[i] + k0 + p * 64),
                    (__attribute__((address_space(3))) void*)(As + p * 8192 + (w * 32 + i * 8) * 64),
                    16, 0, 0);
                __builtin_amdgcn_global_load_lds(
                    (__attribute__((address_space(1))) void*)(bp[i] + k0 + p * 64),
                    (__attribute__((address_space(3))) void*)(Bs + p * 8192 + (w * 32 + i * 8) * 64),
                    16, 0, 0);
            }
        }
        __syncthreads();
        #pragma unroll
        for (int ks = 0; ks < 4; ks++) {
            const ushort_t* Ab = As + (ks >> 1) * 8192;
            const ushort_t* Bb = Bs + (ks >> 1) * 8192;
            const int cidx = (((ks & 1) * 4 + quad) ^ swzr) * 8;
            bf16x8 af[4], bfr[4];
            #pragma unroll
            for (int mt = 0; mt < 4; mt++)
                af[mt] = *(const bf16x8*)(Ab + (wr * 64 + mt * 16 + lrow) * 64 + cidx);
            #pragma unroll
            for (int nt = 0; nt < 4; nt++)
                bfr[nt] = *(const bf16x8*)(Bb + (wc * 64 + nt * 16 + lrow) * 64 + cidx);
            #pragma unroll
            for (int mt = 0; mt < 4; mt++)
                #pragma unroll
                for (int nt = 0; nt < 4; nt++)
                    acc[mt][nt] = __builtin_amdgcn_mfma_f32_16x16x32_bf16(af[mt], bfr[nt], acc[mt][nt], 0, 0, 0);
        }
    }
}

// GEMM1 (compacted M, raw-feat input, LN fused into epilogue, BK=128):
// Hc[base_a + i][d] = gelu( r_t*(featT[tok_i] @ w1s[a] - m_t*cs1[a]) + bias1[a] )
__global__ __launch_bounds__(256) void gemm1c(const ushort_t* __restrict__ featT,
                                              const ushort_t* __restrict__ w1t,
                                              const float* __restrict__ bias1,
                                              const float* __restrict__ cs1,
                                              const float* __restrict__ sumv,
                                              const float* __restrict__ sumq,
                                              const int* __restrict__ tokw,
                                              const int* __restrict__ cnt,
                                              ushort_t* __restrict__ Hc) {
    int a = blockIdx.z;
    int mcount = cnt[a];
    int m0 = blockIdx.y * 128;
    if (m0 >= mcount) return;
    int n0 = blockIdx.x * 128;
    int base = 0;
    for (int a2 = 0; a2 < a; a2++) base += cnt[a2];

    __shared__ __align__(16) ushort_t As[2 * 128 * 64];
    __shared__ __align__(16) ushort_t Bs[2 * 128 * 64];

    int tid = threadIdx.x, lane = tid & 63, w = tid >> 6;
    int lrow8 = lane >> 3;
    int scol = ((lane & 7) ^ lrow8) * 8;
    int srowl = w * 32 + lrow8;

    const ushort_t* ap[4];
    const ushort_t* bp[4];
    #pragma unroll
    for (int i = 0; i < 4; i++) {
        int rt = tokw[a * NTOK + m0 + srowl + i * 8] & (NTOK - 1);
        ap[i] = featT + (size_t)rt * C_DIM + scol;
        bp[i] = w1t + ((size_t)a * CR + n0 + srowl + i * 8) * C_DIM + scol;
    }

    f32x4 acc[4][4];
    gemm_core_bk128(ap, bp, C_DIM, As, Bs, acc);

    int wr = w >> 1, wc = w & 1, lrow = lane & 15, quad = lane >> 4;
    float bi[4], cs[4];
    #pragma unroll
    for (int nt = 0; nt < 4; nt++) {
        int col = a * CR + n0 + wc * 64 + nt * 16 + lrow;
        bi[nt] = bias1[col];
        cs[nt] = cs1[col];
    }
    #pragma unroll
    for (int mt = 0; mt < 4; mt++)
        #pragma unroll
        for (int r = 0; r < 4; r++) {
            int i_row = m0 + wr * 64 + mt * 16 + quad * 4 + r;
            bool live = i_row < mcount;
            int t = tokw[a * NTOK + i_row] & (NTOK - 1);
            float m = sumv[t] * (1.f / C_DIM);
            float q = sumq[t] * (1.f / C_DIM);
            float rn = rsqrtf(q - m * m + 1e-5f);
            #pragma unroll
            for (int nt = 0; nt < 4; nt++) {
                int col = n0 + wc * 64 + nt * 16 + lrow;
                float v = rn * (acc[mt][nt][r] - m * cs[nt]) + bi[nt];
                if (live)
                    Hc[(size_t)(base + i_row) * CR + col] = f2bf(fast_gelu(v));
            }
        }
}

// GEMM2 (compacted, per-adapter K=256, BK=64): O[base_a + i][c] = Hc_a[i] @ w2[a]
__global__ __launch_bounds__(256) void gemm2c(const ushort_t* __restrict__ Hc,
                                              const ushort_t* __restrict__ w2t,
                                              const int* __restrict__ cnt,
                                              ushort_t* __restrict__ O) {
    int a = blockIdx.z;
    int mcount = cnt[a];
    int m0 = blockIdx.y * 128;
    if (m0 >= mcount) return;
    int n0 = blockIdx.x * 128;
    int base = 0;
    for (int a2 = 0; a2 < a; a2++) base += cnt[a2];

    __shared__ __align__(16) ushort_t As[128 * 64];
    __shared__ __align__(16) ushort_t Bs[128 * 64];

    int tid = threadIdx.x, lane = tid & 63, w = tid >> 6;
    int lrow8 = lane >> 3;
    int scol = ((lane & 7) ^ lrow8) * 8;
    int srowl = w * 32 + lrow8;

    const ushort_t* ap[4];
    const ushort_t* bp[4];
    #pragma unroll
    for (int i = 0; i < 4; i++) {
        ap[i] = Hc + (size_t)(base + m0 + srowl + i * 8) * CR + scol;
        bp[i] = w2t + (size_t)(n0 + srowl + i * 8) * KG2 + a * CR + scol;
    }

    f32x4 acc[4][4];
    gemm_core_ptrs(ap, bp, CR, As, Bs, acc);

    int wr = w >> 1, wc = w & 1, lrow = lane & 15, quad = lane >> 4;
    #pragma unroll
    for (int mt = 0; mt < 4; mt++)
        #pragma unroll
        for (int r = 0; r < 4; r++) {
            int i_row = m0 + wr * 64 + mt * 16 + quad * 4 + r;
            bool live = i_row < mcount;
            #pragma unroll
            for (int nt = 0; nt < 4; nt++) {
                int col = n0 + wc * 64 + nt * 16 + lrow;
                if (live)
                    O[(size_t)(base + i_row) * C_DIM + col] = f2bf(acc[mt][nt][r]);
            }
        }
}

// final gather: out[b][c][p] = feat + sum_j w_j * O[gpos_j(t)][c]
// O-read vectorized: 8-lane group per token, bf16x8 (16B) loads.
__global__ __launch_bounds__(256) void finalk2(const ushort_t* __restrict__ O,
                                               const int* __restrict__ tokmap,
                                               const int* __restrict__ cnt,
                                               const float* __restrict__ feat,
                                               float* __restrict__ out) {
    int p0 = blockIdx.x * 64, c0 = blockIdx.y * 64, b = blockIdx.z;
    __shared__ float lds[64][65];
    __shared__ int pbase[A_N];
    int tid = threadIdx.x, lo = tid & 63, hi = tid >> 6;
    if (tid < A_N) {
        int s = 0;
        for (int k = 0; k < tid; k++) s += cnt[k];
        pbase[tid] = s;
    }
    __syncthreads();
    int t_l = tid >> 3, cg = tid & 7;
    #pragma unroll
    for (int ii = 0; ii < 2; ii++) {
        int tl = ii * 32 + t_l;
        int t = b * HW_N + p0 + tl;
        float val8[8];
        #pragma unroll
        for (int k = 0; k < 8; k++) val8[k] = 0.f;
        #pragma unroll
        for (int j = 0; j < 3; j++) {
            int e = tokmap[t * 3 + j];
            float wv = (float)(e >> 17) * (1.0f / 3.0f);
            int a2 = (e >> 13) & 15;
            int row = pbase[a2] + (e & 8191);
            bf16x8 v = *(const bf16x8*)(O + (size_t)row * C_DIM + c0 + cg * 8);
            #pragma unroll
            for (int k = 0; k < 8; k++)
                val8[k] += wv * bf2f((ushort_t)v[k]);
        }
        #pragma unroll
        for (int k = 0; k < 8; k++)
            lds[tl][cg * 8 + k] = val8[k];      // 2-way bank alias max (free, m136)
    }
    __syncthreads();
    #pragma unroll
    for (int i = 0; i < 16; i++) {
        int c_l = i * 4 + hi;
        size_t o = ((size_t)b * C_DIM + c0 + c_l) * HW_N + p0 + lo;
        out[o] = lds[lo][c_l] + feat[o];
    }
}

// ---------------- launch ----------------
extern "C" void kernel_launch(void* const* d_in, const int* in_sizes, int n_in,
                              void* d_out, int out_size, void* d_ws, size_t ws_size,
                              hipStream_t stream) {
    (void)in_sizes; (void)n_in; (void)out_size; (void)ws_size;
    const float* feat = (const float*)d_in[0];
    const float* ar   = (const float*)d_in[1];
    const float* ln_s = (const float*)d_in[2];
    const float* ln_b = (const float*)d_in[3];
    const float* w1   = (const float*)d_in[4];
    const float* w2   = (const float*)d_in[5];
    float* out = (float*)d_out;
    char* ws = (char*)d_ws;

    // ---- zero-init region (zeroed by zerok kernel: atomic targets only) ----
    float*    bias1  = (float*)(ws + 0);          // 10,240
    float*    cs1    = (float*)(ws + 10240);      // 10,240 -> 20,480
    int*      cnt    = (int*)(ws + 20480);        // 40 (pad to 20,736)
    float*    sumv   = (float*)(ws + 20736);      // 32,768 -> 53,504
    float*    sumq   = (float*)(ws + 53504);      // 32,768 -> 86,272
    const size_t ZERO_BYTES = 86272;              // /16 = 5392 f32x4
    // ---- uninitialized region ----
    int*      tokmap = (int*)(ws + 86272);        // 98,304   -> 184,576
    int*      tokw   = (int*)(ws + 184576);       // 327,680  -> 512,256
    ushort_t* w1t    = (ushort_t*)(ws + 512256);  // 5,242,880 -> 5,755,136
    ushort_t* w2t    = (ushort_t*)(ws + 5755136); // 5,242,880 -> 10,998,016
    ushort_t* featT  = (ushort_t*)(ws + 10998016);// 16,777,216 -> 27,775,232
    ushort_t* Hc     = (ushort_t*)(ws + 27775232);// 12,648,448 -> 40,423,680
    ushort_t* O      = (ushort_t*)(ws + 40423680);// 50,331,648 -> 90,755,328

    dim3 blk(256);
    zerok<<<dim3((int)(ZERO_BYTES / 16 + 255) / 256), blk, 0, stream>>>((float*)ws, (int)(ZERO_BYTES / 16));
    prep_all<<<dim3(3360), blk, 0, stream>>>(w1, w2, ln_s, ln_b, feat, ar,
                                             w1t, w2t, bias1, cs1, sumv, sumq,
                                             cnt, tokw, tokmap, featT);
    gemm1c<<<dim3(2, 64, A_N), blk, 0, stream>>>(featT, w1t, bias1, cs1, sumv, sumq,
                                                 tokw, cnt, Hc);
    gemm2c<<<dim3(8, 64, A_N), blk, 0, stream>>>(Hc, w2t, cnt, O);
    finalk2<<<dim3(64, 16, B_N), blk, 0, stream>>>(O, tokmap, cnt, feat, out);
}